// Round 12
// baseline (297.613 us; speedup 1.0000x reference)
//
#include <hip/hip_runtime.h>
#include <hip/hip_bf16.h>

// ---------------------------------------------------------------------------
// SemanticActor fused forward — Round 12: 4-wave blocks, 64 cols/wave.
// R11 post-mortem: MFMA busy = 37.6us = the 86-GFLOP floor; LDS ~57us is the
// tall pole, and its 8x read amplification = 256/(cols per wave) is invariant
// to TROWS. Fix: 64 cols/wave (w2f[16][2]=128 regs; total/wave ~235 of the
// 256 unified budget) -> amplification 4x. Block = 4 waves, TROWS=32; LDS
// 40KB/block; 2048 regs / ~235 = 8 waves/CU = TWO desynchronized blocks/CU
// (the overlap R6 couldn't get). Biases loaded inline per pair (saves 32
// regs); W3 frags overwrite w2f in place. Same 1-barrier/pair pipeline,
// same prep kernel as R11. Watch WRITE_SIZE: ballooning = w2f spilled.
// ---------------------------------------------------------------------------

#define B_TOTAL 65536
#define TROWS   32

typedef __attribute__((ext_vector_type(8)))  short s8v;   // 8 x bf16
typedef __attribute__((ext_vector_type(16))) float f16v;  // 32x32 C/D

__constant__ int c_PI[6] = {0,0,1,1,2,2};
__constant__ int c_PJ[6] = {1,2,0,2,0,1};
__constant__ int c_PF[6] = {0,0,1,0,1,1};
__constant__ int c_INV[2][30] = {
  {0,1,2,3,4,5,6,7,8,9,10,11,12,13,-1,14,15,16,-1,-1,17,18,-1,-1,-1,19,-1,-1,-1,-1},
  {0,1,2,3,4,5,6,7,8,9,-1,-1,-1,-1,10,-1,-1,-1,11,12,-1,-1,13,14,15,-1,16,17,18,19}};

static __device__ __forceinline__ short bf16s(float v) {
  __hip_bfloat16 h = __float2bfloat16(v);
  union { __hip_bfloat16 h; short s; } u; u.h = h; return u.s;
}
static __device__ __forceinline__ unsigned pk2(float a, float b) {
  __hip_bfloat162 h = __float22bfloat162_rn(float2{a, b});
  union { __hip_bfloat162 h2; unsigned u; } cv; cv.h2 = h;
  return cv.u;
}

// ---- prep: identical to R11 (A-frag-major 1KB blocks, coalesced) -----------
__global__ __launch_bounds__(256)
void prep_weights(const float* __restrict__ phi_w1,
                  const float* __restrict__ phi_b1,
                  const float* __restrict__ phi_w2,
                  const float* __restrict__ rho_w1,
                  const float* __restrict__ mean_w,
                  const float* __restrict__ logstd_w,
                  __hip_bfloat16* __restrict__ W1P,
                  __hip_bfloat16* __restrict__ W2f,
                  __hip_bfloat16* __restrict__ W3f,
                  __hip_bfloat16* __restrict__ W4f) {
  const int wid  = (blockIdx.x * blockDim.x + threadIdx.x) >> 6;
  const int lane = threadIdx.x & 63;
  const int l31  = lane & 31;
  const int kq   = (lane >> 5) * 8;
  if (wid >= 656) return;
  union { short s[8]; s8v v; } o;
  __hip_bfloat16* dst;
  if (wid < 384) {
    const int p = wid >> 6, rem = wid & 63;
    const int n = ((rem >> 3) * 32) + l31;        // out col 0..255
    const int ksb = (rem & 7) * 16;
    const int f = c_PF[p], oi = c_PI[p], oj = c_PJ[p];
#pragma unroll
    for (int j = 0; j < 8; ++j) {
      int k = ksb + kq + j;                        // raw dim 0..127
      float v = 0.0f;
      if (k < 30)       { int t = c_INV[f][k];      if (t >= 0) v = phi_w1[t * 256 + n]; }
      else if (k < 60)  { int t = c_INV[f][k - 30]; if (t >= 0) v = phi_w1[(30 + t) * 256 + n]; }
      else if (k < 70)  { v = phi_w1[(20 + k - 60) * 256 + n]; }
      else if (k < 115) { int q = (k - 70) / 15, t = (k - 70) - q * 15;
                          int c = (q == oi) ? 50 + t : (q == oj) ? 65 + t : -1;
                          if (c >= 0) v = phi_w1[c * 256 + n]; }
      else if (k == 115) v = phi_b1[n];   // bias via ones-column
      o.s[j] = bf16s(v);
    }
    dst = W1P + wid * 512 + lane * 8;
  } else if (wid < 512) {
    const int r = wid - 384;
    const int n = ((r >> 4) * 32) + l31;
    const int ksb = (r & 15) * 16;
#pragma unroll
    for (int j = 0; j < 8; ++j)
      o.s[j] = bf16s(phi_w2[(ksb + kq + j) * 256 + n]);
    dst = W2f + r * 512 + lane * 8;
  } else if (wid < 640) {
    const int r = wid - 512;
    const int n = ((r >> 4) * 32) + l31;
    const int ksb = (r & 15) * 16;
#pragma unroll
    for (int j = 0; j < 8; ++j)
      o.s[j] = bf16s(rho_w1[(ksb + kq + j) * 256 + n]);
    dst = W3f + r * 512 + lane * 8;
  } else {
    const int ks = wid - 640;
    const int n = l31;                      // head col: <4 mean, <8 logstd
#pragma unroll
    for (int j = 0; j < 8; ++j) {
      int k = ks * 16 + kq + j;
      float v = (n < 4) ? mean_w[k * 4 + n]
              : (n < 8) ? logstd_w[k * 4 + (n - 4)] : 0.0f;
      o.s[j] = bf16s(v);
    }
    dst = W4f + ks * 512 + lane * 8;
  }
  *reinterpret_cast<s8v*>(dst) = o.v;
}

// ---- main: 256 threads (4 waves), 32 rows/block; wave w = 64 out cols ------
__global__ __launch_bounds__(256, 2)
void actor_main(const float* __restrict__ obs, const float* __restrict__ ag,
                const float* __restrict__ g,
                const __hip_bfloat16* __restrict__ W1P,
                const __hip_bfloat16* __restrict__ W2f,
                const __hip_bfloat16* __restrict__ W3f,
                const __hip_bfloat16* __restrict__ W4f,
                const float* __restrict__ b2, const float* __restrict__ b3,
                const float* __restrict__ meanb,
                const float* __restrict__ logstdb,
                float* __restrict__ out) {
  __shared__ __align__(16) __hip_bfloat16 rawS[8 * 512];        // 8 KB (K=128)
  __shared__ __align__(16) __hip_bfloat16 Hs[2][16 * 512];      // 32 KB

  const int tid  = threadIdx.x;
  const int lane = tid & 63;
  const int w    = tid >> 6;     // wave 0..3 -> out cols [w*64, w*64+64)
  const int l31  = lane & 31;
  const int q5   = lane >> 5;
  const int r0   = blockIdx.x * TROWS;

  // persistent W2 A-frags: 16 ks x 2 col-tiles = 128 regs
  s8v w2f[16][2];
#pragma unroll
  for (int ct = 0; ct < 2; ++ct)
#pragma unroll
    for (int ks = 0; ks < 16; ++ks)
      w2f[ks][ct] = *(const s8v*)&W2f[((w * 2 + ct) * 16 + ks) * 512 + lane * 8];

  // stage raw [ag|g|obs|1|0] K=128, B-frag-major (2 b128 stores/thread)
  {
    const int row = tid & 31;            // adjacent lanes -> adjacent rows
    const int c0  = (tid >> 5) * 16;     // 8 groups x 16 cols
    const float* agr = ag  + (size_t)(r0 + row) * 30;
    const float* gr  = g   + (size_t)(r0 + row) * 30;
    const float* obr = obs + (size_t)(r0 + row) * 55;
    union { short s[16]; s8v v[2]; } o;
#pragma unroll
    for (int cc = 0; cc < 16; ++cc) {
      int c = c0 + cc;
      float v;
      if      (c < 30)  v = agr[c];
      else if (c < 60)  v = gr[c - 30];
      else if (c < 115) v = obr[c - 60];
      else if (c == 115) v = 1.0f;
      else              v = 0.0f;
      o.s[cc] = bf16s(v);
    }
    const int base = (c0 >> 4) * 512 + row * 8;
    *reinterpret_cast<s8v*>(&rawS[base])       = o.v[0];   // k&15 in [0,8)
    *reinterpret_cast<s8v*>(&rawS[base + 256]) = o.v[1];   // k&15 in [8,16)
  }

  f16v agg[2] = {};

  __syncthreads();  // rawS staged

  // GEMM1(pair p) -> Hs[p&1]: D = W1P[p](A, mt=w*2+ct) x raw(B); K=128
  auto gemm1 = [&](int p) {
    const __hip_bfloat16* wb = W1P + p * 32768;
    __hip_bfloat16* buf = &Hs[p & 1][0];
    f16v a1[2] = {};
#pragma unroll
    for (int ks = 0; ks < 8; ++ks) {
      s8v rb = *(const s8v*)&rawS[ks * 512 + lane * 8];
      s8v w10 = *(const s8v*)&wb[((w * 2 + 0) * 8 + ks) * 512 + lane * 8];
      s8v w11 = *(const s8v*)&wb[((w * 2 + 1) * 8 + ks) * 512 + lane * 8];
      a1[0] = __builtin_amdgcn_mfma_f32_32x32x16_bf16(w10, rb, a1[0], 0, 0, 0);
      a1[1] = __builtin_amdgcn_mfma_f32_32x32x16_bf16(w11, rb, a1[1], 0, 0, 0);
    }
    // epilogue: relu (bias via ones-col); hidden col m = w*64+ct*32+8gp+4q5+r
    // -> block ks = w*4 + ct*2 + (gp>>1), lane' = l31+32*(gp&1), off 4q5
#pragma unroll
    for (int ct = 0; ct < 2; ++ct)
#pragma unroll
      for (int gp = 0; gp < 4; ++gp) {
        float v0 = fmaxf(a1[ct][4 * gp + 0], 0.f);
        float v1 = fmaxf(a1[ct][4 * gp + 1], 0.f);
        float v2 = fmaxf(a1[ct][4 * gp + 2], 0.f);
        float v3 = fmaxf(a1[ct][4 * gp + 3], 0.f);
        uint2 U; U.x = pk2(v0, v1); U.y = pk2(v2, v3);
        *reinterpret_cast<uint2*>(
          &buf[(w * 4 + ct * 2 + (gp >> 1)) * 512 +
               (l31 + 32 * (gp & 1)) * 8 + 4 * q5]) = U;
      }
  };

  gemm1(0);
  __syncthreads();

#pragma unroll 1
  for (int p = 0; p < 6; ++p) {
    // GEMM2(p): D = W2(A) x H(B); K=256; agg += relu(D + b2)
    const __hip_bfloat16* buf = &Hs[p & 1][0];
    f16v a2[2] = {};
#pragma unroll
    for (int ks = 0; ks < 16; ++ks) {
      s8v hb = *(const s8v*)&buf[ks * 512 + lane * 8];
      a2[0] = __builtin_amdgcn_mfma_f32_32x32x16_bf16(w2f[ks][0], hb, a2[0], 0, 0, 0);
      a2[1] = __builtin_amdgcn_mfma_f32_32x32x16_bf16(w2f[ks][1], hb, a2[1], 0, 0, 0);
    }
#pragma unroll
    for (int ct = 0; ct < 2; ++ct)
#pragma unroll
      for (int gp = 0; gp < 4; ++gp) {
        const float4 bb = *(const float4*)&b2[w * 64 + ct * 32 + 8 * gp + 4 * q5];
        agg[ct][4 * gp + 0] += fmaxf(a2[ct][4 * gp + 0] + bb.x, 0.f);
        agg[ct][4 * gp + 1] += fmaxf(a2[ct][4 * gp + 1] + bb.y, 0.f);
        agg[ct][4 * gp + 2] += fmaxf(a2[ct][4 * gp + 2] + bb.z, 0.f);
        agg[ct][4 * gp + 3] += fmaxf(a2[ct][4 * gp + 3] + bb.w, 0.f);
      }

    // GEMM1(p+1) into the other buffer (its last readers finished GEMM2(p-1)
    // before the previous barrier)
    if (p < 5) gemm1(p + 1);
    __syncthreads();
  }

  // W3 A-frags overwrite w2f in place (guarantees register reuse)
#pragma unroll
  for (int ct = 0; ct < 2; ++ct)
#pragma unroll
    for (int ks = 0; ks < 16; ++ks)
      w2f[ks][ct] = *(const s8v*)&W3f[((w * 2 + ct) * 16 + ks) * 512 + lane * 8];

  // stash agg (bf16) into Hs[0], B-frag-major (same transform as gemm1 epi)
  {
    __hip_bfloat16* bufA = &Hs[0][0];
#pragma unroll
    for (int ct = 0; ct < 2; ++ct)
#pragma unroll
      for (int gp = 0; gp < 4; ++gp) {
        uint2 U;
        U.x = pk2(agg[ct][4 * gp + 0], agg[ct][4 * gp + 1]);
        U.y = pk2(agg[ct][4 * gp + 2], agg[ct][4 * gp + 3]);
        *reinterpret_cast<uint2*>(
          &bufA[(w * 4 + ct * 2 + (gp >> 1)) * 512 +
                (l31 + 32 * (gp & 1)) * 8 + 4 * q5]) = U;
      }
  }
  __syncthreads();

  // GEMM3: hr = relu(W3(A) x agg(B) + b3); reads Hs[0], writes Hs[1]
  {
    const __hip_bfloat16* bufA = &Hs[0][0];
    f16v a3[2] = {};
#pragma unroll
    for (int ks = 0; ks < 16; ++ks) {
      s8v hb = *(const s8v*)&bufA[ks * 512 + lane * 8];
      a3[0] = __builtin_amdgcn_mfma_f32_32x32x16_bf16(w2f[ks][0], hb, a3[0], 0, 0, 0);
      a3[1] = __builtin_amdgcn_mfma_f32_32x32x16_bf16(w2f[ks][1], hb, a3[1], 0, 0, 0);
    }
    __hip_bfloat16* bufB = &Hs[1][0];
#pragma unroll
    for (int ct = 0; ct < 2; ++ct)
#pragma unroll
      for (int gp = 0; gp < 4; ++gp) {
        const float4 bb = *(const float4*)&b3[w * 64 + ct * 32 + 8 * gp + 4 * q5];
        float v0 = fmaxf(a3[ct][4 * gp + 0] + bb.x, 0.f);
        float v1 = fmaxf(a3[ct][4 * gp + 1] + bb.y, 0.f);
        float v2 = fmaxf(a3[ct][4 * gp + 2] + bb.z, 0.f);
        float v3 = fmaxf(a3[ct][4 * gp + 3] + bb.w, 0.f);
        uint2 U; U.x = pk2(v0, v1); U.y = pk2(v2, v3);
        *reinterpret_cast<uint2*>(
          &bufB[(w * 4 + ct * 2 + (gp >> 1)) * 512 +
                (l31 + 32 * (gp & 1)) * 8 + 4 * q5]) = U;
      }
  }
  __syncthreads();

  // GEMM4: heads; wave 0 only; reads Hs[1]
  if (w == 0) {
    const __hip_bfloat16* bufB = &Hs[1][0];
    f16v a4 = {};
#pragma unroll
    for (int ks = 0; ks < 16; ++ks) {
      s8v w4 = *(const s8v*)&W4f[ks * 512 + lane * 8];
      s8v hf = *(const s8v*)&bufB[ks * 512 + lane * 8];
      a4 = __builtin_amdgcn_mfma_f32_32x32x16_bf16(w4, hf, a4, 0, 0, 0);
    }
    // D: head col m = 4*q5 + r (regs 0..3); batch row = l31
    const int row = r0 + l31;
    if (q5 == 0) {            // m=0..3: mean
      float4 mb = *(const float4*)meanb;
      float4 o;
      o.x = a4[0] + mb.x; o.y = a4[1] + mb.y;
      o.z = a4[2] + mb.z; o.w = a4[3] + mb.w;
      *reinterpret_cast<float4*>(&out[(size_t)row * 4]) = o;
    } else {                  // m=4..7: logstd (clipped)
      float4 lb = *(const float4*)logstdb;
      float4 o;
      o.x = fminf(fmaxf(a4[0] + lb.x, -20.f), 2.f);
      o.y = fminf(fmaxf(a4[1] + lb.y, -20.f), 2.f);
      o.z = fminf(fmaxf(a4[2] + lb.z, -20.f), 2.f);
      o.w = fminf(fmaxf(a4[3] + lb.w, -20.f), 2.f);
      *reinterpret_cast<float4*>(&out[(size_t)B_TOTAL * 4 + (size_t)row * 4]) = o;
    }
  }
}

extern "C" void kernel_launch(void* const* d_in, const int* in_sizes, int n_in,
                              void* d_out, int out_size, void* d_ws, size_t ws_size,
                              hipStream_t stream) {
  const float* obs      = (const float*)d_in[0];
  const float* ag       = (const float*)d_in[1];
  const float* g        = (const float*)d_in[2];
  const float* phi_w1   = (const float*)d_in[3];
  const float* phi_b1   = (const float*)d_in[4];
  const float* phi_w2   = (const float*)d_in[5];
  const float* phi_b2   = (const float*)d_in[6];
  const float* rho_w1   = (const float*)d_in[7];
  const float* rho_b1   = (const float*)d_in[8];
  const float* mean_w   = (const float*)d_in[9];
  const float* mean_b   = (const float*)d_in[10];
  const float* logstd_w = (const float*)d_in[11];
  const float* logstd_b = (const float*)d_in[12];
  float* out = (float*)d_out;

  // ws (bf16): W1P 6x32768 | W2f 65536 | W3f 65536 | W4f 8192 elems
  char* ws = (char*)d_ws;
  __hip_bfloat16* W1P = (__hip_bfloat16*)(ws);
  __hip_bfloat16* W2f = (__hip_bfloat16*)(ws + 393216);
  __hip_bfloat16* W3f = (__hip_bfloat16*)(ws + 393216 + 131072);
  __hip_bfloat16* W4f = (__hip_bfloat16*)(ws + 393216 + 262144);

  prep_weights<<<164, 256, 0, stream>>>(phi_w1, phi_b1, phi_w2, rho_w1,
                                        mean_w, logstd_w, W1P, W2f, W3f, W4f);
  actor_main<<<B_TOTAL / TROWS, 256, 0, stream>>>(
      obs, ag, g, W1P, W2f, W3f, W4f, phi_b2, rho_b1, mean_b, logstd_b, out);
}

// Round 13
// 271.474 us; speedup vs baseline: 1.0963x; 1.0963x over previous
//
#include <hip/hip_runtime.h>
#include <hip/hip_bf16.h>

// ---------------------------------------------------------------------------
// SemanticActor fused forward — Round 13: R12 shape, R11 register budget.
// R12 post-mortem: 512 regs/SIMD pool (m69) + ~128 arch-VGPR compiler cap;
// w2f[16][2]=128 persistent could never fit -> K-loop spills (WRITE 127MB).
// But R12 proved 256-thread blocks DO co-reside 2/CU (8 waves/CU @ 4-wave
// blocks). R13: keep 4-wave/TROWS=32/64-cols-per-wave (4x LDS amplification,
// 2 desync blocks/CU) but persist only HALF the W2 slice (w2p[16]=64 regs,
// ct0); stream ct1 frags from L2 inside the ks loop (same pattern GEMM1
// already uses for W1P). Per-wave ~208 total regs = R11's proven budget.
// LDS 40KB/block. GEMM3 same split. Watch WRITE_SIZE: ~2MB = no spill.
// ---------------------------------------------------------------------------

#define B_TOTAL 65536
#define TROWS   32

typedef __attribute__((ext_vector_type(8)))  short s8v;   // 8 x bf16
typedef __attribute__((ext_vector_type(16))) float f16v;  // 32x32 C/D

__constant__ int c_PI[6] = {0,0,1,1,2,2};
__constant__ int c_PJ[6] = {1,2,0,2,0,1};
__constant__ int c_PF[6] = {0,0,1,0,1,1};
__constant__ int c_INV[2][30] = {
  {0,1,2,3,4,5,6,7,8,9,10,11,12,13,-1,14,15,16,-1,-1,17,18,-1,-1,-1,19,-1,-1,-1,-1},
  {0,1,2,3,4,5,6,7,8,9,-1,-1,-1,-1,10,-1,-1,-1,11,12,-1,-1,13,14,15,-1,16,17,18,19}};

static __device__ __forceinline__ short bf16s(float v) {
  __hip_bfloat16 h = __float2bfloat16(v);
  union { __hip_bfloat16 h; short s; } u; u.h = h; return u.s;
}
static __device__ __forceinline__ unsigned pk2(float a, float b) {
  __hip_bfloat162 h = __float22bfloat162_rn(float2{a, b});
  union { __hip_bfloat162 h2; unsigned u; } cv; cv.h2 = h;
  return cv.u;
}

// ---- prep: identical to R11/R12 (A-frag-major 1KB blocks, coalesced) -------
__global__ __launch_bounds__(256)
void prep_weights(const float* __restrict__ phi_w1,
                  const float* __restrict__ phi_b1,
                  const float* __restrict__ phi_w2,
                  const float* __restrict__ rho_w1,
                  const float* __restrict__ mean_w,
                  const float* __restrict__ logstd_w,
                  __hip_bfloat16* __restrict__ W1P,
                  __hip_bfloat16* __restrict__ W2f,
                  __hip_bfloat16* __restrict__ W3f,
                  __hip_bfloat16* __restrict__ W4f) {
  const int wid  = (blockIdx.x * blockDim.x + threadIdx.x) >> 6;
  const int lane = threadIdx.x & 63;
  const int l31  = lane & 31;
  const int kq   = (lane >> 5) * 8;
  if (wid >= 656) return;
  union { short s[8]; s8v v; } o;
  __hip_bfloat16* dst;
  if (wid < 384) {
    const int p = wid >> 6, rem = wid & 63;
    const int n = ((rem >> 3) * 32) + l31;        // out col 0..255
    const int ksb = (rem & 7) * 16;
    const int f = c_PF[p], oi = c_PI[p], oj = c_PJ[p];
#pragma unroll
    for (int j = 0; j < 8; ++j) {
      int k = ksb + kq + j;                        // raw dim 0..127
      float v = 0.0f;
      if (k < 30)       { int t = c_INV[f][k];      if (t >= 0) v = phi_w1[t * 256 + n]; }
      else if (k < 60)  { int t = c_INV[f][k - 30]; if (t >= 0) v = phi_w1[(30 + t) * 256 + n]; }
      else if (k < 70)  { v = phi_w1[(20 + k - 60) * 256 + n]; }
      else if (k < 115) { int q = (k - 70) / 15, t = (k - 70) - q * 15;
                          int c = (q == oi) ? 50 + t : (q == oj) ? 65 + t : -1;
                          if (c >= 0) v = phi_w1[c * 256 + n]; }
      else if (k == 115) v = phi_b1[n];   // bias via ones-column
      o.s[j] = bf16s(v);
    }
    dst = W1P + wid * 512 + lane * 8;
  } else if (wid < 512) {
    const int r = wid - 384;
    const int n = ((r >> 4) * 32) + l31;
    const int ksb = (r & 15) * 16;
#pragma unroll
    for (int j = 0; j < 8; ++j)
      o.s[j] = bf16s(phi_w2[(ksb + kq + j) * 256 + n]);
    dst = W2f + r * 512 + lane * 8;
  } else if (wid < 640) {
    const int r = wid - 512;
    const int n = ((r >> 4) * 32) + l31;
    const int ksb = (r & 15) * 16;
#pragma unroll
    for (int j = 0; j < 8; ++j)
      o.s[j] = bf16s(rho_w1[(ksb + kq + j) * 256 + n]);
    dst = W3f + r * 512 + lane * 8;
  } else {
    const int ks = wid - 640;
    const int n = l31;                      // head col: <4 mean, <8 logstd
#pragma unroll
    for (int j = 0; j < 8; ++j) {
      int k = ks * 16 + kq + j;
      float v = (n < 4) ? mean_w[k * 4 + n]
              : (n < 8) ? logstd_w[k * 4 + (n - 4)] : 0.0f;
      o.s[j] = bf16s(v);
    }
    dst = W4f + ks * 512 + lane * 8;
  }
  *reinterpret_cast<s8v*>(dst) = o.v;
}

// ---- main: 256 threads (4 waves), 32 rows/block; wave w = 64 out cols ------
__global__ __launch_bounds__(256, 2)
void actor_main(const float* __restrict__ obs, const float* __restrict__ ag,
                const float* __restrict__ g,
                const __hip_bfloat16* __restrict__ W1P,
                const __hip_bfloat16* __restrict__ W2f,
                const __hip_bfloat16* __restrict__ W3f,
                const __hip_bfloat16* __restrict__ W4f,
                const float* __restrict__ b2, const float* __restrict__ b3,
                const float* __restrict__ meanb,
                const float* __restrict__ logstdb,
                float* __restrict__ out) {
  __shared__ __align__(16) __hip_bfloat16 rawS[8 * 512];        // 8 KB (K=128)
  __shared__ __align__(16) __hip_bfloat16 Hs[2][16 * 512];      // 32 KB

  const int tid  = threadIdx.x;
  const int lane = tid & 63;
  const int w    = tid >> 6;     // wave 0..3 -> out cols [w*64, w*64+64)
  const int l31  = lane & 31;
  const int q5   = lane >> 5;
  const int r0   = blockIdx.x * TROWS;

  // persistent W2 A-frags: ct=0 only (mt = w*2), 64 regs
  s8v w2p[16];
#pragma unroll
  for (int ks = 0; ks < 16; ++ks)
    w2p[ks] = *(const s8v*)&W2f[((w * 2) * 16 + ks) * 512 + lane * 8];

  // stage raw [ag|g|obs|1|0] K=128, B-frag-major (2 b128 stores/thread)
  {
    const int row = tid & 31;            // adjacent lanes -> adjacent rows
    const int c0  = (tid >> 5) * 16;     // 8 groups x 16 cols
    const float* agr = ag  + (size_t)(r0 + row) * 30;
    const float* gr  = g   + (size_t)(r0 + row) * 30;
    const float* obr = obs + (size_t)(r0 + row) * 55;
    union { short s[16]; s8v v[2]; } o;
#pragma unroll
    for (int cc = 0; cc < 16; ++cc) {
      int c = c0 + cc;
      float v;
      if      (c < 30)  v = agr[c];
      else if (c < 60)  v = gr[c - 30];
      else if (c < 115) v = obr[c - 60];
      else if (c == 115) v = 1.0f;
      else              v = 0.0f;
      o.s[cc] = bf16s(v);
    }
    const int base = (c0 >> 4) * 512 + row * 8;
    *reinterpret_cast<s8v*>(&rawS[base])       = o.v[0];   // k&15 in [0,8)
    *reinterpret_cast<s8v*>(&rawS[base + 256]) = o.v[1];   // k&15 in [8,16)
  }

  f16v agg[2] = {};

  __syncthreads();  // rawS staged

  // GEMM1(pair p) -> Hs[p&1]: D = W1P[p](A, mt=w*2+ct) x raw(B); K=128
  auto gemm1 = [&](int p) {
    const __hip_bfloat16* wb = W1P + p * 32768;
    __hip_bfloat16* buf = &Hs[p & 1][0];
    f16v a1[2] = {};
#pragma unroll
    for (int ks = 0; ks < 8; ++ks) {
      s8v rb = *(const s8v*)&rawS[ks * 512 + lane * 8];
      s8v w10 = *(const s8v*)&wb[((w * 2 + 0) * 8 + ks) * 512 + lane * 8];
      s8v w11 = *(const s8v*)&wb[((w * 2 + 1) * 8 + ks) * 512 + lane * 8];
      a1[0] = __builtin_amdgcn_mfma_f32_32x32x16_bf16(w10, rb, a1[0], 0, 0, 0);
      a1[1] = __builtin_amdgcn_mfma_f32_32x32x16_bf16(w11, rb, a1[1], 0, 0, 0);
    }
    // epilogue: relu (bias via ones-col); hidden col m = w*64+ct*32+8gp+4q5+r
    // -> block ks = w*4 + ct*2 + (gp>>1), lane' = l31+32*(gp&1), off 4q5
#pragma unroll
    for (int ct = 0; ct < 2; ++ct)
#pragma unroll
      for (int gp = 0; gp < 4; ++gp) {
        float v0 = fmaxf(a1[ct][4 * gp + 0], 0.f);
        float v1 = fmaxf(a1[ct][4 * gp + 1], 0.f);
        float v2 = fmaxf(a1[ct][4 * gp + 2], 0.f);
        float v3 = fmaxf(a1[ct][4 * gp + 3], 0.f);
        uint2 U; U.x = pk2(v0, v1); U.y = pk2(v2, v3);
        *reinterpret_cast<uint2*>(
          &buf[(w * 4 + ct * 2 + (gp >> 1)) * 512 +
               (l31 + 32 * (gp & 1)) * 8 + 4 * q5]) = U;
      }
  };

  gemm1(0);
  __syncthreads();

#pragma unroll 1
  for (int p = 0; p < 6; ++p) {
    // GEMM2(p): ct0 from persistent w2p, ct1 streamed from L2 (hits L1/L2)
    const __hip_bfloat16* buf = &Hs[p & 1][0];
    f16v a2[2] = {};
#pragma unroll
    for (int ks = 0; ks < 16; ++ks) {
      s8v hb = *(const s8v*)&buf[ks * 512 + lane * 8];
      s8v w2s = *(const s8v*)&W2f[((w * 2 + 1) * 16 + ks) * 512 + lane * 8];
      a2[0] = __builtin_amdgcn_mfma_f32_32x32x16_bf16(w2p[ks], hb, a2[0], 0, 0, 0);
      a2[1] = __builtin_amdgcn_mfma_f32_32x32x16_bf16(w2s, hb, a2[1], 0, 0, 0);
    }
#pragma unroll
    for (int ct = 0; ct < 2; ++ct)
#pragma unroll
      for (int gp = 0; gp < 4; ++gp) {
        const float4 bb = *(const float4*)&b2[w * 64 + ct * 32 + 8 * gp + 4 * q5];
        agg[ct][4 * gp + 0] += fmaxf(a2[ct][4 * gp + 0] + bb.x, 0.f);
        agg[ct][4 * gp + 1] += fmaxf(a2[ct][4 * gp + 1] + bb.y, 0.f);
        agg[ct][4 * gp + 2] += fmaxf(a2[ct][4 * gp + 2] + bb.z, 0.f);
        agg[ct][4 * gp + 3] += fmaxf(a2[ct][4 * gp + 3] + bb.w, 0.f);
      }

    // GEMM1(p+1) into the other buffer (its last readers finished GEMM2(p-1)
    // before the previous barrier)
    if (p < 5) gemm1(p + 1);
    __syncthreads();
  }

  // W3 ct0 frags overwrite w2p in place; ct1 streamed in GEMM3
#pragma unroll
  for (int ks = 0; ks < 16; ++ks)
    w2p[ks] = *(const s8v*)&W3f[((w * 2) * 16 + ks) * 512 + lane * 8];

  // stash agg (bf16) into Hs[0], B-frag-major (same transform as gemm1 epi)
  {
    __hip_bfloat16* bufA = &Hs[0][0];
#pragma unroll
    for (int ct = 0; ct < 2; ++ct)
#pragma unroll
      for (int gp = 0; gp < 4; ++gp) {
        uint2 U;
        U.x = pk2(agg[ct][4 * gp + 0], agg[ct][4 * gp + 1]);
        U.y = pk2(agg[ct][4 * gp + 2], agg[ct][4 * gp + 3]);
        *reinterpret_cast<uint2*>(
          &bufA[(w * 4 + ct * 2 + (gp >> 1)) * 512 +
                (l31 + 32 * (gp & 1)) * 8 + 4 * q5]) = U;
      }
  }
  __syncthreads();

  // GEMM3: hr = relu(W3(A) x agg(B) + b3); reads Hs[0], writes Hs[1]
  {
    const __hip_bfloat16* bufA = &Hs[0][0];
    f16v a3[2] = {};
#pragma unroll
    for (int ks = 0; ks < 16; ++ks) {
      s8v hb = *(const s8v*)&bufA[ks * 512 + lane * 8];
      s8v w3s = *(const s8v*)&W3f[((w * 2 + 1) * 16 + ks) * 512 + lane * 8];
      a3[0] = __builtin_amdgcn_mfma_f32_32x32x16_bf16(w2p[ks], hb, a3[0], 0, 0, 0);
      a3[1] = __builtin_amdgcn_mfma_f32_32x32x16_bf16(w3s, hb, a3[1], 0, 0, 0);
    }
    __hip_bfloat16* bufB = &Hs[1][0];
#pragma unroll
    for (int ct = 0; ct < 2; ++ct)
#pragma unroll
      for (int gp = 0; gp < 4; ++gp) {
        const float4 bb = *(const float4*)&b3[w * 64 + ct * 32 + 8 * gp + 4 * q5];
        float v0 = fmaxf(a3[ct][4 * gp + 0] + bb.x, 0.f);
        float v1 = fmaxf(a3[ct][4 * gp + 1] + bb.y, 0.f);
        float v2 = fmaxf(a3[ct][4 * gp + 2] + bb.z, 0.f);
        float v3 = fmaxf(a3[ct][4 * gp + 3] + bb.w, 0.f);
        uint2 U; U.x = pk2(v0, v1); U.y = pk2(v2, v3);
        *reinterpret_cast<uint2*>(
          &bufB[(w * 4 + ct * 2 + (gp >> 1)) * 512 +
                (l31 + 32 * (gp & 1)) * 8 + 4 * q5]) = U;
      }
  }
  __syncthreads();

  // GEMM4: heads; wave 0 only; reads Hs[1]
  if (w == 0) {
    const __hip_bfloat16* bufB = &Hs[1][0];
    f16v a4 = {};
#pragma unroll
    for (int ks = 0; ks < 16; ++ks) {
      s8v w4 = *(const s8v*)&W4f[ks * 512 + lane * 8];
      s8v hf = *(const s8v*)&bufB[ks * 512 + lane * 8];
      a4 = __builtin_amdgcn_mfma_f32_32x32x16_bf16(w4, hf, a4, 0, 0, 0);
    }
    // D: head col m = 4*q5 + r (regs 0..3); batch row = l31
    const int row = r0 + l31;
    if (q5 == 0) {            // m=0..3: mean
      float4 mb = *(const float4*)meanb;
      float4 o;
      o.x = a4[0] + mb.x; o.y = a4[1] + mb.y;
      o.z = a4[2] + mb.z; o.w = a4[3] + mb.w;
      *reinterpret_cast<float4*>(&out[(size_t)row * 4]) = o;
    } else {                  // m=4..7: logstd (clipped)
      float4 lb = *(const float4*)logstdb;
      float4 o;
      o.x = fminf(fmaxf(a4[0] + lb.x, -20.f), 2.f);
      o.y = fminf(fmaxf(a4[1] + lb.y, -20.f), 2.f);
      o.z = fminf(fmaxf(a4[2] + lb.z, -20.f), 2.f);
      o.w = fminf(fmaxf(a4[3] + lb.w, -20.f), 2.f);
      *reinterpret_cast<float4*>(&out[(size_t)B_TOTAL * 4 + (size_t)row * 4]) = o;
    }
  }
}

extern "C" void kernel_launch(void* const* d_in, const int* in_sizes, int n_in,
                              void* d_out, int out_size, void* d_ws, size_t ws_size,
                              hipStream_t stream) {
  const float* obs      = (const float*)d_in[0];
  const float* ag       = (const float*)d_in[1];
  const float* g        = (const float*)d_in[2];
  const float* phi_w1   = (const float*)d_in[3];
  const float* phi_b1   = (const float*)d_in[4];
  const float* phi_w2   = (const float*)d_in[5];
  const float* phi_b2   = (const float*)d_in[6];
  const float* rho_w1   = (const float*)d_in[7];
  const float* rho_b1   = (const float*)d_in[8];
  const float* mean_w   = (const float*)d_in[9];
  const float* mean_b   = (const float*)d_in[10];
  const float* logstd_w = (const float*)d_in[11];
  const float* logstd_b = (const float*)d_in[12];
  float* out = (float*)d_out;

  // ws (bf16): W1P 6x32768 | W2f 65536 | W3f 65536 | W4f 8192 elems
  char* ws = (char*)d_ws;
  __hip_bfloat16* W1P = (__hip_bfloat16*)(ws);
  __hip_bfloat16* W2f = (__hip_bfloat16*)(ws + 393216);
  __hip_bfloat16* W3f = (__hip_bfloat16*)(ws + 393216 + 131072);
  __hip_bfloat16* W4f = (__hip_bfloat16*)(ws + 393216 + 262144);

  prep_weights<<<164, 256, 0, stream>>>(phi_w1, phi_b1, phi_w2, rho_w1,
                                        mean_w, logstd_w, W1P, W2f, W3f, W4f);
  actor_main<<<B_TOTAL / TROWS, 256, 0, stream>>>(
      obs, ag, g, W1P, W2f, W3f, W4f, phi_b2, rho_b1, mean_b, logstd_b, out);
}